// Round 6
// baseline (200.858 us; speedup 1.0000x reference)
//
#include <hip/hip_runtime.h>
#include <hip/hip_bf16.h>
#include <math.h>

#define D_DIM 2048
#define L_DIM 64
#define E_NUM 64
#define H_DIM 64

typedef float f32x4_t __attribute__((ext_vector_type(4)));
typedef __bf16 bf16x8_t __attribute__((ext_vector_type(8)));

// ---------------- workspace layout (bytes) ----------------
// WS_UPART: 512*2048 f32 partial sums of u      (4 MB)
// WS_U:     2048 f32 u = x^T wout               (8 KB)
// WS_V:     64 f32 v
// WS_META:  sel[2] (int) + g[2] (float)
// WS_WB:    tiled bf16 expert weights [32 kstep][128 row][64] (512 KB)
// WS_XB:    tiled bf16 x [64 mtile][32 kstep][128 row][64]    (32 MB)
// WS_PART:  4*8192*128 f32 split-K GEMM partials (16 MB)
#define WS_UPART 0u
#define WS_U     (512u * 2048u * 4u)
#define WS_V     (WS_U + 2048u * 4u)
#define WS_META  (WS_V + 256u)
#define WS_WB    (WS_META + 64u)
#define WS_XB    (WS_WB + 128u * 2048u * 2u)
#define WS_PART  (WS_XB + 8192u * 2048u * 2u)

// Tiled layouts (bf16 elem offsets). Swizzle baked into storage:
//   chunk kc (16B) of row r within a kstep tile lives at slot (kc ^ (r&7)).
//   xb_t: mtile*262144 + kstep*8192 + (row&127)*64 + slot*8
//   wb_t:               kstep*8192 +  row      *64 + slot*8

// ---------------- kernel 1: u_part + tiled bf16 cast of x ----------------
__global__ void k_upart(const float* __restrict__ x, const float* __restrict__ wout,
                        float* __restrict__ upart, __hip_bfloat16* __restrict__ xbt) {
  const int t = threadIdx.x;            // 256 threads x 8 cols
  const int d8 = t * 8;
  const int s0 = blockIdx.x * 16;       // 512 blocks x 16 rows
  const int kstep = d8 >> 6;            // 0..31
  const int kc = (d8 >> 3) & 7;         // 16B chunk within kstep
  float a0 = 0.f, a1 = 0.f, a2 = 0.f, a3 = 0.f;
  float a4 = 0.f, a5 = 0.f, a6 = 0.f, a7 = 0.f;
  for (int i = 0; i < 16; ++i) {
    const int row = s0 + i;
    const float w = wout[row];
    const float4 pa = *reinterpret_cast<const float4*>(x + (size_t)row * D_DIM + d8);
    const float4 pb = *reinterpret_cast<const float4*>(x + (size_t)row * D_DIM + d8 + 4);
    a0 += pa.x * w; a1 += pa.y * w; a2 += pa.z * w; a3 += pa.w * w;
    a4 += pb.x * w; a5 += pb.y * w; a6 += pb.z * w; a7 += pb.w * w;
    union { __hip_bfloat16 h[8]; uint4 u; } pk;
    pk.h[0] = __float2bfloat16(pa.x); pk.h[1] = __float2bfloat16(pa.y);
    pk.h[2] = __float2bfloat16(pa.z); pk.h[3] = __float2bfloat16(pa.w);
    pk.h[4] = __float2bfloat16(pb.x); pk.h[5] = __float2bfloat16(pb.y);
    pk.h[6] = __float2bfloat16(pb.z); pk.h[7] = __float2bfloat16(pb.w);
    const int mt = row >> 7, rl = row & 127;
    const size_t off = (size_t)mt * 262144 + kstep * 8192 + rl * 64 +
                       ((kc ^ (rl & 7)) * 8);
    *reinterpret_cast<uint4*>(xbt + off) = pk.u;
  }
  float* up = upart + (size_t)blockIdx.x * D_DIM + d8;
  *reinterpret_cast<float4*>(up)     = make_float4(a0, a1, a2, a3);
  *reinterpret_cast<float4*>(up + 4) = make_float4(a4, a5, a6, a7);
}

// ---------------- kernel 1b: u[d] = sum_c u_part[c][d] ----------------
__global__ void k_ufinish(const float* __restrict__ upart, float* __restrict__ u) {
  const int d = blockIdx.x * 256 + threadIdx.x;  // grid 8 x 256
  float s = 0.f;
#pragma unroll 8
  for (int c = 0; c < 512; ++c) s += upart[(size_t)c * D_DIM + d];
  u[d] = s;
}

// ---------------- kernel 2a: v[h] = Wg_in[h,:] . u ----------------
__global__ void k_v(const float* __restrict__ wg_in, const float* __restrict__ u,
                    float* __restrict__ v) {
  const int h = blockIdx.x;  // 64 blocks
  const int t = threadIdx.x; // 256 threads
  const float4* wr = reinterpret_cast<const float4*>(wg_in + (size_t)h * D_DIM);
  const float4* ur = reinterpret_cast<const float4*>(u);
  float s = 0.f;
#pragma unroll
  for (int i = t; i < 512; i += 256) {
    const float4 a = wr[i];
    const float4 b = ur[i];
    s += a.x * b.x + a.y * b.y + a.z * b.z + a.w * b.w;
  }
  __shared__ float red[4];
#pragma unroll
  for (int off = 32; off; off >>= 1) s += __shfl_down(s, off, 64);
  if ((t & 63) == 0) red[t >> 6] = s;
  __syncthreads();
  if (t == 0) v[h] = red[0] + red[1] + red[2] + red[3];
}

// ---------------- kernel 2b: scores, top-2, softmax ----------------
__global__ void k_gate(const float* __restrict__ wg_lin, const float* __restrict__ v,
                       int* __restrict__ sel, float* __restrict__ g) {
  __shared__ float vv[H_DIM];
  __shared__ float sc[E_NUM];
  const int t = threadIdx.x;  // 64 threads
  vv[t] = v[t];
  __syncthreads();
  float s = 0.f;
#pragma unroll 8
  for (int hh = 0; hh < H_DIM; ++hh) s += wg_lin[t * H_DIM + hh] * vv[hh];
  sc[t] = s;
  __syncthreads();
  if (t == 0) {
    int b1 = 0; float m1 = sc[0];
    for (int e = 1; e < E_NUM; ++e) { if (sc[e] > m1) { m1 = sc[e]; b1 = e; } }
    int b2 = -1; float m2 = -3.4e38f;
    for (int e = 0; e < E_NUM; ++e) {
      if (e != b1 && sc[e] > m2) { m2 = sc[e]; b2 = e; }
    }
    const float e2 = expf(m2 - m1);
    const float g0 = 1.0f / (1.0f + e2);
    sel[0] = b1; sel[1] = b2;
    g[0] = g0; g[1] = 1.0f - g0;
  }
}

// ---------------- kernel 2c: tiled bf16 cast of selected experts ----------
__global__ void k_wb(const float* __restrict__ we, const int* __restrict__ sel,
                     __hip_bfloat16* __restrict__ wbt) {
  const int n = blockIdx.x;         // 128 rows = 2 experts x 64
  const int e = sel[n >> 6];
  const int l = n & 63;
  const float* src = we + ((size_t)e * L_DIM + l) * D_DIM;
  const int t = threadIdx.x;        // 256 threads, 8 elems each
  const int d8 = t * 8;
  const int kstep = d8 >> 6;
  const int kc = (d8 >> 3) & 7;
  const float4 a = reinterpret_cast<const float4*>(src)[2 * t];
  const float4 b = reinterpret_cast<const float4*>(src)[2 * t + 1];
  union { __hip_bfloat16 h[8]; uint4 u; } pk;
  pk.h[0] = __float2bfloat16(a.x); pk.h[1] = __float2bfloat16(a.y);
  pk.h[2] = __float2bfloat16(a.z); pk.h[3] = __float2bfloat16(a.w);
  pk.h[4] = __float2bfloat16(b.x); pk.h[5] = __float2bfloat16(b.y);
  pk.h[6] = __float2bfloat16(b.z); pk.h[7] = __float2bfloat16(b.w);
  const size_t off = (size_t)kstep * 8192 + n * 64 + ((kc ^ (n & 7)) * 8);
  *reinterpret_cast<uint4*>(wbt + off) = pk.u;
}

// ---------------- kernel 3: bf16 MFMA GEMM -> f32 partials ----------------
// Grid (64, 4): blockIdx.x = M-tile (128 rows), blockIdx.y = K-chunk (512).
// 512 threads = 8 waves (2 Mw x 4 Nw); wave tile 64x32; 8 K-steps of BK=64.
// STAGING EXPERIMENT: reg-staging (global_load_dwordx4 -> VGPR -> ds_write_b128)
// replaces global_load_lds entirely; theory is the LDS-DMA path serializes at
// ~150 cy/wave-instr/CU and has been the invariant ~40us wall for 5 rounds.
// T14 split: loads(next) issued at top of step, ds_write after the post-compute
// barrier (HBM/L2 latency hides under ds_read+MFMA). Double-buffered LDS 64 KB.
// Tiled sources: each K-step's A and B tiles are contiguous 16 KB, swizzle
// pre-baked in storage; LDS image identical to the verified R4 kernel, so all
// fragment reads / swizzle decode / MFMA math are bit-identical to passing code.
__device__ __forceinline__ float gelu_f(float v) {
  return 0.5f * v * (1.0f + erff(v * 0.70710678118654752440f));
}

__global__ __launch_bounds__(512) void k_moe_gemm(
    const __hip_bfloat16* __restrict__ xbt, const __hip_bfloat16* __restrict__ wbt,
    float* __restrict__ part) {
  __shared__ __align__(16) unsigned char lds[2][32768];  // [A 16K | B 16K] x2

  const int tid = threadIdx.x;
  const int w = tid >> 6, lane = tid & 63;
  const int wm = w >> 2, wn = w & 3;           // wave M-slot (0..1), N-slot (0..3)
  const int m0 = blockIdx.x * 128;
  const int kg = blockIdx.y;                   // K-chunk 0..3
  const int fr = lane & 15, fq = lane >> 4;
  const size_t abase = (size_t)blockIdx.x * 262144;  // elems into xbt

  uint4 ra[2], rb[2];                          // in-flight staging regs

  auto ldreg = [&](int kk) {
    const size_t tbase = (size_t)(kg * 8 + kk) * 8192;  // kstep tile, elems
#pragma unroll
    for (int ph = 0; ph < 2; ++ph) {
      const int c = ph * 512 + tid;            // 16B chunk 0..1023, linear
      ra[ph] = *reinterpret_cast<const uint4*>(xbt + abase + tbase + c * 8);
      rb[ph] = *reinterpret_cast<const uint4*>(wbt + tbase + c * 8);
    }
  };
  auto wlds = [&](int buf) {
#pragma unroll
    for (int ph = 0; ph < 2; ++ph) {
      const int c = ph * 512 + tid;
      *reinterpret_cast<uint4*>(&lds[buf][c * 16]) = ra[ph];
      *reinterpret_cast<uint4*>(&lds[buf][16384 + c * 16]) = rb[ph];
    }
  };

  f32x4_t acc[4][2];
#pragma unroll
  for (int mf = 0; mf < 4; ++mf)
#pragma unroll
    for (int nf = 0; nf < 2; ++nf) acc[mf][nf] = (f32x4_t){0.f, 0.f, 0.f, 0.f};

  ldreg(0);
  wlds(0);
  __syncthreads();

  for (int kk = 0; kk < 8; ++kk) {
    const int cur = kk & 1;
    if (kk < 7) ldreg(kk + 1);   // issue next-tile loads; return hides under compute
    const unsigned char* ldsA = lds[cur];
    const unsigned char* ldsB = lds[cur] + 16384;
    union fragu { uint4 u; bf16x8_t v; };
    fragu af[4][2], bf_[2][2];
#pragma unroll
    for (int mf = 0; mf < 4; ++mf)
#pragma unroll
      for (int ks = 0; ks < 2; ++ks) {
        const int ar = wm * 64 + mf * 16 + fr;
        const int kq = ks * 4 + fq;
        af[mf][ks].u = *reinterpret_cast<const uint4*>(
            ldsA + ar * 128 + ((kq ^ (ar & 7)) * 16));
      }
#pragma unroll
    for (int nf = 0; nf < 2; ++nf)
#pragma unroll
      for (int ks = 0; ks < 2; ++ks) {
        const int br = wn * 32 + nf * 16 + fr;
        const int kq = ks * 4 + fq;
        bf_[nf][ks].u = *reinterpret_cast<const uint4*>(
            ldsB + br * 128 + ((kq ^ (br & 7)) * 16));
      }
#pragma unroll
    for (int mf = 0; mf < 4; ++mf)
#pragma unroll
      for (int nf = 0; nf < 2; ++nf) {
        acc[mf][nf] = __builtin_amdgcn_mfma_f32_16x16x32_bf16(
            af[mf][0].v, bf_[nf][0].v, acc[mf][nf], 0, 0, 0);
        acc[mf][nf] = __builtin_amdgcn_mfma_f32_16x16x32_bf16(
            af[mf][1].v, bf_[nf][1].v, acc[mf][nf], 0, 0, 0);
      }
    __syncthreads();                    // all waves done reading lds[cur]
    if (kk < 7) {
      wlds(cur ^ 1);                    // compiler waits vmcnt for ra/rb here
      __syncthreads();                  // lds[cur^1] ready for next step
    }
  }

  // ---- epilogue: direct f32 stores of partials (no LDS round-trip) ----
#pragma unroll
  for (int mf = 0; mf < 4; ++mf)
#pragma unroll
    for (int nf = 0; nf < 2; ++nf)
#pragma unroll
      for (int reg = 0; reg < 4; ++reg) {
        const int r = m0 + wm * 64 + mf * 16 + fq * 4 + reg;
        const int c = wn * 32 + nf * 16 + fr;
        part[((size_t)kg * 8192 + r) * 128 + c] = acc[mf][nf][reg];
      }
}

// ---------------- kernel 4: reduce partials + normalize + gelu + combine ----
__global__ __launch_bounds__(256) void k_finish(const float* __restrict__ part,
                                                const float* __restrict__ gw,
                                                float* __restrict__ out) {
  __shared__ float z[32 * 132];
  __shared__ float ps[32 * 8];
  const int tid = threadIdx.x;
  const int m0 = blockIdx.x * 32;   // 256 blocks
  const float g0 = gw[0], g1 = gw[1];
  const size_t KSTRIDE = (size_t)8192 * 128;
#pragma unroll
  for (int p = 0; p < 4; ++p) {
    const int idx = p * 256 + tid;
    const int r = idx >> 5, c4 = (idx & 31) * 4;
    const float* pp = part + ((size_t)(m0 + r)) * 128 + c4;
    const f32x4_t s = *reinterpret_cast<const f32x4_t*>(pp)
                    + *reinterpret_cast<const f32x4_t*>(pp + KSTRIDE)
                    + *reinterpret_cast<const f32x4_t*>(pp + 2 * KSTRIDE)
                    + *reinterpret_cast<const f32x4_t*>(pp + 3 * KSTRIDE);
    z[r * 132 + c4 + 0] = s[0];
    z[r * 132 + c4 + 1] = s[1];
    z[r * 132 + c4 + 2] = s[2];
    z[r * 132 + c4 + 3] = s[3];
  }
  __syncthreads();
  {
    const int r = tid >> 3, seg = tid & 7;
    float s = 0.f;
#pragma unroll
    for (int i2 = 0; i2 < 16; ++i2) {
      const float t2 = z[r * 132 + seg * 16 + i2];
      s += t2 * t2;
    }
    ps[r * 8 + seg] = s;
  }
  __syncthreads();
  {
    const int r = tid >> 3, j = tid & 7;
    const float s0 = ps[r * 8 + 0] + ps[r * 8 + 1] + ps[r * 8 + 2] + ps[r * 8 + 3];
    const float s1 = ps[r * 8 + 4] + ps[r * 8 + 5] + ps[r * 8 + 6] + ps[r * 8 + 7];
    const float i0 = 1.0f / fmaxf(sqrtf(s0), 1e-12f);
    const float i1 = 1.0f / fmaxf(sqrtf(s1), 1e-12f);
    float o[8];
#pragma unroll
    for (int i2 = 0; i2 < 8; ++i2) {
      const int c = j * 8 + i2;
      const float za = z[r * 132 + c] * i0;
      const float zb2 = z[r * 132 + 64 + c] * i1;
      o[i2] = g0 * gelu_f(za) + g1 * gelu_f(zb2);
    }
    float4* op = reinterpret_cast<float4*>(out + (size_t)(m0 + r) * 64 + j * 8);
    op[0] = make_float4(o[0], o[1], o[2], o[3]);
    op[1] = make_float4(o[4], o[5], o[6], o[7]);
  }
}

// ---------------- launch ----------------
extern "C" void kernel_launch(void* const* d_in, const int* in_sizes, int n_in,
                              void* d_out, int out_size, void* d_ws, size_t ws_size,
                              hipStream_t stream) {
  (void)in_sizes; (void)n_in; (void)out_size; (void)ws_size;
  const float* x      = (const float*)d_in[0];
  const float* wg_in  = (const float*)d_in[1];
  const float* wg_lin = (const float*)d_in[2];
  const float* wg_out = (const float*)d_in[3];
  const float* we     = (const float*)d_in[4];
  float* out = (float*)d_out;
  char* ws = (char*)d_ws;

  float* upart = (float*)(ws + WS_UPART);
  float* u     = (float*)(ws + WS_U);
  float* v     = (float*)(ws + WS_V);
  int*   sel   = (int*)(ws + WS_META);
  float* g     = (float*)(ws + WS_META + 8);
  __hip_bfloat16* wbt = (__hip_bfloat16*)(ws + WS_WB);
  __hip_bfloat16* xbt = (__hip_bfloat16*)(ws + WS_XB);
  float* part = (float*)(ws + WS_PART);

  k_upart  <<<512, 256, 0, stream>>>(x, wg_out, upart, xbt);
  k_ufinish<<<8, 256, 0, stream>>>(upart, u);
  k_v      <<<64, 256, 0, stream>>>(wg_in, u, v);
  k_gate   <<<1, 64, 0, stream>>>(wg_lin, v, sel, g);
  k_wb     <<<128, 256, 0, stream>>>(we, sel, wbt);
  k_moe_gemm<<<dim3(64, 4), 512, 0, stream>>>(xbt, wbt, part);
  k_finish <<<256, 256, 0, stream>>>(part, g, out);
}

// Round 7
// 160.362 us; speedup vs baseline: 1.2525x; 1.2525x over previous
//
#include <hip/hip_runtime.h>
#include <hip/hip_bf16.h>
#include <math.h>

#define D_DIM 2048
#define L_DIM 64
#define E_NUM 64
#define H_DIM 64

typedef float f32x4_t __attribute__((ext_vector_type(4)));
typedef __bf16 bf16x8_t __attribute__((ext_vector_type(8)));

// ---------------- workspace layout (bytes) ----------------
// WS_UPART: 128*2048 f32 partial sums of u      (1 MB)
// WS_U:     2048 f32 u = x^T wout               (8 KB)
// WS_V:     64 f32 v
// WS_META:  sel[2] (int) + g[2] (float)
// WS_WB:    tiled bf16 expert weights [32 kstep][128 row][64] (512 KB)
// WS_PART:  8*8192*128 f32 split-K GEMM partials (32 MB)
#define WS_UPART 0u
#define WS_U     (128u * 2048u * 4u)
#define WS_V     (WS_U + 2048u * 4u)
#define WS_META  (WS_V + 256u)
#define WS_WB    (WS_META + 64u)
#define WS_PART  (WS_WB + 128u * 2048u * 2u)

// wbt tiled layout (bf16 elem offsets), swizzle baked into storage:
//   chunk kc (16B) of row r within kstep tile lives at slot (kc ^ (r&7)):
//   wbt: kstep*8192 + row*64 + slot*8

// ---------------- kernel 1: u_part (R1-verified lean version) ----------------
__global__ void k_upart(const float* __restrict__ x, const float* __restrict__ wout,
                        float* __restrict__ upart) {
  const int d4 = (blockIdx.x * 256 + threadIdx.x) * 4;  // gridDim.x == 2
  const int s0 = blockIdx.y * 64;                        // gridDim.y == 128
  const float* xp = x + (size_t)s0 * D_DIM + d4;
  float4 acc = make_float4(0.f, 0.f, 0.f, 0.f);
#pragma unroll 8
  for (int i = 0; i < 64; ++i) {
    const float w = wout[s0 + i];
    const float4 xv = *reinterpret_cast<const float4*>(xp + (size_t)i * D_DIM);
    acc.x += xv.x * w; acc.y += xv.y * w; acc.z += xv.z * w; acc.w += xv.w * w;
  }
  *reinterpret_cast<float4*>(upart + (size_t)blockIdx.y * D_DIM + d4) = acc;
}

// ---------------- kernel 1b: u[d] = sum_c u_part[c][d] ----------------
__global__ void k_ufinish(const float* __restrict__ upart, float* __restrict__ u) {
  const int d = blockIdx.x * 256 + threadIdx.x;  // grid 8 x 256
  float s = 0.f;
#pragma unroll 8
  for (int c = 0; c < 128; ++c) s += upart[(size_t)c * D_DIM + d];
  u[d] = s;
}

// ---------------- kernel 2a: v[h] = Wg_in[h,:] . u ----------------
__global__ void k_v(const float* __restrict__ wg_in, const float* __restrict__ u,
                    float* __restrict__ v) {
  const int h = blockIdx.x;  // 64 blocks
  const int t = threadIdx.x; // 256 threads
  const float4* wr = reinterpret_cast<const float4*>(wg_in + (size_t)h * D_DIM);
  const float4* ur = reinterpret_cast<const float4*>(u);
  float s = 0.f;
#pragma unroll
  for (int i = t; i < 512; i += 256) {
    const float4 a = wr[i];
    const float4 b = ur[i];
    s += a.x * b.x + a.y * b.y + a.z * b.z + a.w * b.w;
  }
  __shared__ float red[4];
#pragma unroll
  for (int off = 32; off; off >>= 1) s += __shfl_down(s, off, 64);
  if ((t & 63) == 0) red[t >> 6] = s;
  __syncthreads();
  if (t == 0) v[h] = red[0] + red[1] + red[2] + red[3];
}

// ---------------- kernel 2b: scores, top-2, softmax ----------------
__global__ void k_gate(const float* __restrict__ wg_lin, const float* __restrict__ v,
                       int* __restrict__ sel, float* __restrict__ g) {
  __shared__ float vv[H_DIM];
  __shared__ float sc[E_NUM];
  const int t = threadIdx.x;  // 64 threads
  vv[t] = v[t];
  __syncthreads();
  float s = 0.f;
#pragma unroll 8
  for (int hh = 0; hh < H_DIM; ++hh) s += wg_lin[t * H_DIM + hh] * vv[hh];
  sc[t] = s;
  __syncthreads();
  if (t == 0) {
    int b1 = 0; float m1 = sc[0];
    for (int e = 1; e < E_NUM; ++e) { if (sc[e] > m1) { m1 = sc[e]; b1 = e; } }
    int b2 = -1; float m2 = -3.4e38f;
    for (int e = 0; e < E_NUM; ++e) {
      if (e != b1 && sc[e] > m2) { m2 = sc[e]; b2 = e; }
    }
    const float e2 = expf(m2 - m1);
    const float g0 = 1.0f / (1.0f + e2);
    sel[0] = b1; sel[1] = b2;
    g[0] = g0; g[1] = 1.0f - g0;
  }
}

// ---------------- kernel 2c: tiled bf16 cast of selected experts ----------
__global__ void k_wb(const float* __restrict__ we, const int* __restrict__ sel,
                     __hip_bfloat16* __restrict__ wbt) {
  const int n = blockIdx.x;         // 128 rows = 2 experts x 64
  const int e = sel[n >> 6];
  const int l = n & 63;
  const float* src = we + ((size_t)e * L_DIM + l) * D_DIM;
  const int t = threadIdx.x;        // 256 threads, 8 elems each
  const int d8 = t * 8;
  const int kstep = d8 >> 6;
  const int kc = (d8 >> 3) & 7;
  const float4 a = reinterpret_cast<const float4*>(src)[2 * t];
  const float4 b = reinterpret_cast<const float4*>(src)[2 * t + 1];
  union { __hip_bfloat16 h[8]; uint4 u; } pk;
  pk.h[0] = __float2bfloat16(a.x); pk.h[1] = __float2bfloat16(a.y);
  pk.h[2] = __float2bfloat16(a.z); pk.h[3] = __float2bfloat16(a.w);
  pk.h[4] = __float2bfloat16(b.x); pk.h[5] = __float2bfloat16(b.y);
  pk.h[6] = __float2bfloat16(b.z); pk.h[7] = __float2bfloat16(b.w);
  const size_t off = (size_t)kstep * 8192 + n * 64 + ((kc ^ (n & 7)) * 8);
  *reinterpret_cast<uint4*>(wbt + off) = pk.u;
}

// ---------------- kernel 3: bf16 MFMA GEMM -> f32 partials ----------------
// Grid (128, 8) = 1024 blocks = 4 blocks/CU; block 256 thr = 4 waves (2Mw x 2Nw).
// Tile 64(M) x 128(N), K-chunk 256 = 4 steps of BK=64.
// A: staged from f32 x via reg-cvt (R0-verified 144B-padded-row path) — no xbt.
// B: contiguous 16KB gload_lds from tiled wbt (swizzle pre-baked, R4-verified).
// LDS 25.6 KB -> 4 blocks/CU co-resident; independent blocks overlap each
// other's barrier drains (m114); per-CU B-staging = 256 gload_lds wave-instr.
__device__ __forceinline__ void async_ld16(const void* gp, void* lp) {
  __builtin_amdgcn_global_load_lds(
      (const __attribute__((address_space(1))) unsigned int*)gp,
      (__attribute__((address_space(3))) unsigned int*)lp, 16, 0, 0);
}

__device__ __forceinline__ float gelu_f(float v) {
  return 0.5f * v * (1.0f + erff(v * 0.70710678118654752440f));
}

__global__ __launch_bounds__(256, 4) void k_moe_gemm(
    const float* __restrict__ x, const __hip_bfloat16* __restrict__ wbt,
    float* __restrict__ part) {
  __shared__ __align__(16) unsigned char lds[64 * 144 + 16384];  // A 9216 | B 16384
  unsigned char* ldsA = lds;
  unsigned char* ldsB = lds + 64 * 144;

  const int tid = threadIdx.x;
  const int w = tid >> 6, lane = tid & 63;
  const int wm = w >> 1, wn = w & 1;           // 2x2 wave grid, wave tile 32x64
  const int mb = blockIdx.x;                   // M-tile (64 rows)
  const int kg = blockIdx.y;                   // K-split 0..7 (256 K each)
  const int fr = lane & 15, fq = lane >> 4;
  const int m0 = mb * 64;

  f32x4_t acc[2][4];
#pragma unroll
  for (int mf = 0; mf < 2; ++mf)
#pragma unroll
    for (int nf = 0; nf < 4; ++nf) acc[mf][nf] = (f32x4_t){0.f, 0.f, 0.f, 0.f};

  for (int kk = 0; kk < 4; ++kk) {
    const int kstep = kg * 4 + kk;
    const int k0 = kstep * 64;
    if (kk) __syncthreads();
    // ---- stage B: contiguous 16KB via gload_lds (issue first, fly during A) --
#pragma unroll
    for (int ph = 0; ph < 4; ++ph) {
      const int c = ph * 256 + tid;            // 16B chunk 0..1023, linear
      async_ld16(wbt + (size_t)kstep * 8192 + c * 8, ldsB + c * 16);
    }
    // ---- stage A: 512 chunks (2/thread), f32 global -> bf16 -> LDS ----
#pragma unroll
    for (int ph = 0; ph < 2; ++ph) {
      const int c = ph * 256 + tid;
      const int r = c >> 3, c8 = (c & 7) * 8;
      const float* gp = x + (size_t)(m0 + r) * D_DIM + k0 + c8;
      const float4 a0 = *reinterpret_cast<const float4*>(gp);
      const float4 a1 = *reinterpret_cast<const float4*>(gp + 4);
      union { __hip_bfloat16 h[8]; uint4 u; } pk;
      pk.h[0] = __float2bfloat16(a0.x); pk.h[1] = __float2bfloat16(a0.y);
      pk.h[2] = __float2bfloat16(a0.z); pk.h[3] = __float2bfloat16(a0.w);
      pk.h[4] = __float2bfloat16(a1.x); pk.h[5] = __float2bfloat16(a1.y);
      pk.h[6] = __float2bfloat16(a1.z); pk.h[7] = __float2bfloat16(a1.w);
      *reinterpret_cast<uint4*>(ldsA + r * 144 + c8 * 2) = pk.u;
    }
    __syncthreads();
    // ---- fragments ----
    union fragu { uint4 u; bf16x8_t v; };
    fragu af[2][2], bf_[4][2];
#pragma unroll
    for (int mf = 0; mf < 2; ++mf)
#pragma unroll
      for (int ks = 0; ks < 2; ++ks) {
        const int ar = wm * 32 + mf * 16 + fr;
        af[mf][ks].u = *reinterpret_cast<const uint4*>(
            ldsA + ar * 144 + (ks * 4 + fq) * 16);
      }
#pragma unroll
    for (int nf = 0; nf < 4; ++nf)
#pragma unroll
      for (int ks = 0; ks < 2; ++ks) {
        const int br = wn * 64 + nf * 16 + fr;
        const int kq = ks * 4 + fq;
        bf_[nf][ks].u = *reinterpret_cast<const uint4*>(
            ldsB + br * 128 + ((kq ^ (br & 7)) * 16));
      }
#pragma unroll
    for (int mf = 0; mf < 2; ++mf)
#pragma unroll
      for (int nf = 0; nf < 4; ++nf) {
        acc[mf][nf] = __builtin_amdgcn_mfma_f32_16x16x32_bf16(
            af[mf][0].v, bf_[nf][0].v, acc[mf][nf], 0, 0, 0);
        acc[mf][nf] = __builtin_amdgcn_mfma_f32_16x16x32_bf16(
            af[mf][1].v, bf_[nf][1].v, acc[mf][nf], 0, 0, 0);
      }
  }

  // ---- epilogue: direct f32 stores of partials (R4-verified layout) ----
#pragma unroll
  for (int mf = 0; mf < 2; ++mf)
#pragma unroll
    for (int nf = 0; nf < 4; ++nf)
#pragma unroll
      for (int reg = 0; reg < 4; ++reg) {
        const int r = m0 + wm * 32 + mf * 16 + fq * 4 + reg;
        const int c = wn * 64 + nf * 16 + fr;
        part[((size_t)kg * 8192 + r) * 128 + c] = acc[mf][nf][reg];
      }
}

// ---------------- kernel 4: reduce partials + normalize + gelu + combine ----
__global__ __launch_bounds__(256) void k_finish(const float* __restrict__ part,
                                                const float* __restrict__ gw,
                                                float* __restrict__ out) {
  __shared__ float z[32 * 132];
  __shared__ float ps[32 * 8];
  const int tid = threadIdx.x;
  const int m0 = blockIdx.x * 32;   // 256 blocks
  const float g0 = gw[0], g1 = gw[1];
  const size_t KSTRIDE = (size_t)8192 * 128;
#pragma unroll
  for (int p = 0; p < 4; ++p) {
    const int idx = p * 256 + tid;
    const int r = idx >> 5, c4 = (idx & 31) * 4;
    const float* pp = part + ((size_t)(m0 + r)) * 128 + c4;
    f32x4_t s = (f32x4_t){0.f, 0.f, 0.f, 0.f};
#pragma unroll
    for (int kgi = 0; kgi < 8; ++kgi)
      s = s + *reinterpret_cast<const f32x4_t*>(pp + kgi * KSTRIDE);
    z[r * 132 + c4 + 0] = s[0];
    z[r * 132 + c4 + 1] = s[1];
    z[r * 132 + c4 + 2] = s[2];
    z[r * 132 + c4 + 3] = s[3];
  }
  __syncthreads();
  {
    const int r = tid >> 3, seg = tid & 7;
    float s = 0.f;
#pragma unroll
    for (int i2 = 0; i2 < 16; ++i2) {
      const float t2 = z[r * 132 + seg * 16 + i2];
      s += t2 * t2;
    }
    ps[r * 8 + seg] = s;
  }
  __syncthreads();
  {
    const int r = tid >> 3, j = tid & 7;
    const float s0 = ps[r * 8 + 0] + ps[r * 8 + 1] + ps[r * 8 + 2] + ps[r * 8 + 3];
    const float s1 = ps[r * 8 + 4] + ps[r * 8 + 5] + ps[r * 8 + 6] + ps[r * 8 + 7];
    const float i0 = 1.0f / fmaxf(sqrtf(s0), 1e-12f);
    const float i1 = 1.0f / fmaxf(sqrtf(s1), 1e-12f);
    float o[8];
#pragma unroll
    for (int i2 = 0; i2 < 8; ++i2) {
      const int c = j * 8 + i2;
      const float za = z[r * 132 + c] * i0;
      const float zb2 = z[r * 132 + 64 + c] * i1;
      o[i2] = g0 * gelu_f(za) + g1 * gelu_f(zb2);
    }
    float4* op = reinterpret_cast<float4*>(out + (size_t)(m0 + r) * 64 + j * 8);
    op[0] = make_float4(o[0], o[1], o[2], o[3]);
    op[1] = make_float4(o[4], o[5], o[6], o[7]);
  }
}

// ---------------- launch ----------------
extern "C" void kernel_launch(void* const* d_in, const int* in_sizes, int n_in,
                              void* d_out, int out_size, void* d_ws, size_t ws_size,
                              hipStream_t stream) {
  (void)in_sizes; (void)n_in; (void)out_size; (void)ws_size;
  const float* x      = (const float*)d_in[0];
  const float* wg_in  = (const float*)d_in[1];
  const float* wg_lin = (const float*)d_in[2];
  const float* wg_out = (const float*)d_in[3];
  const float* we     = (const float*)d_in[4];
  float* out = (float*)d_out;
  char* ws = (char*)d_ws;

  float* upart = (float*)(ws + WS_UPART);
  float* u     = (float*)(ws + WS_U);
  float* v     = (float*)(ws + WS_V);
  int*   sel   = (int*)(ws + WS_META);
  float* g     = (float*)(ws + WS_META + 8);
  __hip_bfloat16* wbt = (__hip_bfloat16*)(ws + WS_WB);
  float* part = (float*)(ws + WS_PART);

  k_upart  <<<dim3(2, 128), 256, 0, stream>>>(x, wg_out, upart);
  k_ufinish<<<8, 256, 0, stream>>>(upart, u);
  k_v      <<<64, 256, 0, stream>>>(wg_in, u, v);
  k_gate   <<<1, 64, 0, stream>>>(wg_lin, v, sel, g);
  k_wb     <<<128, 256, 0, stream>>>(we, sel, wbt);
  k_moe_gemm<<<dim3(128, 8), 256, 0, stream>>>(x, wbt, part);
  k_finish <<<256, 256, 0, stream>>>(part, g, out);
}

// Round 8
// 159.321 us; speedup vs baseline: 1.2607x; 1.0065x over previous
//
#include <hip/hip_runtime.h>
#include <hip/hip_bf16.h>
#include <math.h>

#define D_DIM 2048
#define L_DIM 64
#define E_NUM 64
#define H_DIM 64

typedef float f32x4_t __attribute__((ext_vector_type(4)));
typedef __bf16 bf16x8_t __attribute__((ext_vector_type(8)));

// ---------------- workspace layout (bytes) ----------------
#define WS_UPART 0u
#define WS_U     (128u * 2048u * 4u)
#define WS_V     (WS_U + 2048u * 4u)
#define WS_META  (WS_V + 256u)
#define WS_WB    (WS_META + 64u)
#define WS_PART  (WS_WB + 128u * 2048u * 2u)

// wbt tiled layout (bf16 elem offsets), swizzle baked into storage:
//   chunk kc (16B) of row r within kstep tile lives at slot (kc ^ (r&7)):
//   wbt: kstep*8192 + row*64 + slot*8

// ---------------- kernel 1: u_part (R1-verified lean version) ----------------
__global__ void k_upart(const float* __restrict__ x, const float* __restrict__ wout,
                        float* __restrict__ upart) {
  const int d4 = (blockIdx.x * 256 + threadIdx.x) * 4;  // gridDim.x == 2
  const int s0 = blockIdx.y * 64;                        // gridDim.y == 128
  const float* xp = x + (size_t)s0 * D_DIM + d4;
  float4 acc = make_float4(0.f, 0.f, 0.f, 0.f);
#pragma unroll 8
  for (int i = 0; i < 64; ++i) {
    const float w = wout[s0 + i];
    const float4 xv = *reinterpret_cast<const float4*>(xp + (size_t)i * D_DIM);
    acc.x += xv.x * w; acc.y += xv.y * w; acc.z += xv.z * w; acc.w += xv.w * w;
  }
  *reinterpret_cast<float4*>(upart + (size_t)blockIdx.y * D_DIM + d4) = acc;
}

// ---------------- kernel 1b: u[d] = sum_c u_part[c][d] ----------------
__global__ void k_ufinish(const float* __restrict__ upart, float* __restrict__ u) {
  const int d = blockIdx.x * 256 + threadIdx.x;  // grid 8 x 256
  float s = 0.f;
#pragma unroll 8
  for (int c = 0; c < 128; ++c) s += upart[(size_t)c * D_DIM + d];
  u[d] = s;
}

// ---------------- kernel 2a: v[h] = Wg_in[h,:] . u ----------------
__global__ void k_v(const float* __restrict__ wg_in, const float* __restrict__ u,
                    float* __restrict__ v) {
  const int h = blockIdx.x;  // 64 blocks
  const int t = threadIdx.x; // 256 threads
  const float4* wr = reinterpret_cast<const float4*>(wg_in + (size_t)h * D_DIM);
  const float4* ur = reinterpret_cast<const float4*>(u);
  float s = 0.f;
#pragma unroll
  for (int i = t; i < 512; i += 256) {
    const float4 a = wr[i];
    const float4 b = ur[i];
    s += a.x * b.x + a.y * b.y + a.z * b.z + a.w * b.w;
  }
  __shared__ float red[4];
#pragma unroll
  for (int off = 32; off; off >>= 1) s += __shfl_down(s, off, 64);
  if ((t & 63) == 0) red[t >> 6] = s;
  __syncthreads();
  if (t == 0) v[h] = red[0] + red[1] + red[2] + red[3];
}

// ---------------- kernel 2b: scores, top-2, softmax ----------------
__global__ void k_gate(const float* __restrict__ wg_lin, const float* __restrict__ v,
                       int* __restrict__ sel, float* __restrict__ g) {
  __shared__ float vv[H_DIM];
  __shared__ float sc[E_NUM];
  const int t = threadIdx.x;  // 64 threads
  vv[t] = v[t];
  __syncthreads();
  float s = 0.f;
#pragma unroll 8
  for (int hh = 0; hh < H_DIM; ++hh) s += wg_lin[t * H_DIM + hh] * vv[hh];
  sc[t] = s;
  __syncthreads();
  if (t == 0) {
    int b1 = 0; float m1 = sc[0];
    for (int e = 1; e < E_NUM; ++e) { if (sc[e] > m1) { m1 = sc[e]; b1 = e; } }
    int b2 = -1; float m2 = -3.4e38f;
    for (int e = 0; e < E_NUM; ++e) {
      if (e != b1 && sc[e] > m2) { m2 = sc[e]; b2 = e; }
    }
    const float e2 = expf(m2 - m1);
    const float g0 = 1.0f / (1.0f + e2);
    sel[0] = b1; sel[1] = b2;
    g[0] = g0; g[1] = 1.0f - g0;
  }
}

// ---------------- kernel 2c: tiled bf16 cast of selected experts ----------
__global__ void k_wb(const float* __restrict__ we, const int* __restrict__ sel,
                     __hip_bfloat16* __restrict__ wbt) {
  const int n = blockIdx.x;         // 128 rows = 2 experts x 64
  const int e = sel[n >> 6];
  const int l = n & 63;
  const float* src = we + ((size_t)e * L_DIM + l) * D_DIM;
  const int t = threadIdx.x;        // 256 threads, 8 elems each
  const int d8 = t * 8;
  const int kstep = d8 >> 6;
  const int kc = (d8 >> 3) & 7;
  const float4 a = reinterpret_cast<const float4*>(src)[2 * t];
  const float4 b = reinterpret_cast<const float4*>(src)[2 * t + 1];
  union { __hip_bfloat16 h[8]; uint4 u; } pk;
  pk.h[0] = __float2bfloat16(a.x); pk.h[1] = __float2bfloat16(a.y);
  pk.h[2] = __float2bfloat16(a.z); pk.h[3] = __float2bfloat16(a.w);
  pk.h[4] = __float2bfloat16(b.x); pk.h[5] = __float2bfloat16(b.y);
  pk.h[6] = __float2bfloat16(b.z); pk.h[7] = __float2bfloat16(b.w);
  const size_t off = (size_t)kstep * 8192 + n * 64 + ((kc ^ (n & 7)) * 8);
  *reinterpret_cast<uint4*>(wbt + off) = pk.u;
}

// ---------------- kernel 3: bf16 MFMA GEMM -> f32 partials ----------------
// Grid (128, 8) = 1024 blocks = 4 blocks/CU; block 256 thr = 4 waves (2Mw x 2Nw).
// Tile 64(M) x 128(N), K-chunk 256 = 4 steps of BK=64.
// PIPELINE (T3/T4): B double-buffered via gload_lds with loads kept in flight
// ACROSS raw s_barriers (counted per-wave vmcnt drains at the latest point);
// A single-buffered 8KB XOR-swizzled (same LDS image as verified R4 layout),
// staged reg->cvt->ds_write with A-loads issued BEFORE B-gloads (sched_barrier
// pinned) so the cvt waits vmcnt(16), leaving B in flight under MFMA+cvt+write.
// LDS = 8192 + 2*16384 = 40960 B -> exactly 4 blocks/CU.
__device__ __forceinline__ void async_ld16(const void* gp, void* lp) {
  __builtin_amdgcn_global_load_lds(
      (const __attribute__((address_space(1))) unsigned int*)gp,
      (__attribute__((address_space(3))) unsigned int*)lp, 16, 0, 0);
}

__device__ __forceinline__ float gelu_f(float v) {
  return 0.5f * v * (1.0f + erff(v * 0.70710678118654752440f));
}

__global__ __launch_bounds__(256, 4) void k_moe_gemm(
    const float* __restrict__ x, const __hip_bfloat16* __restrict__ wbt,
    float* __restrict__ part) {
  __shared__ __align__(16) unsigned char ldsA[8192];        // A 64x[8 slots x16B]
  __shared__ __align__(16) unsigned char ldsB[2][16384];    // B dbuf

  const int tid = threadIdx.x;
  const int w = tid >> 6, lane = tid & 63;
  const int wm = w >> 1, wn = w & 1;           // 2x2 wave grid, wave tile 32x64
  const int mb = blockIdx.x;                   // M-tile (64 rows)
  const int kg = blockIdx.y;                   // K-split 0..7 (256 K each)
  const int fr = lane & 15, fq = lane >> 4;
  const int m0 = mb * 64;

  // A staging geometry: 512 chunks of 16B (2/thread). chunk c: row r=c>>3,
  // k-chunk kc=c&7; LDS slot = kc ^ (r&7) (bakes the same swizzle as wbt).
  const int c0 = tid, c1 = 256 + tid;
  const int r0_ = c0 >> 3, kc0 = c0 & 7, r1_ = c1 >> 3, kc1 = c1 & 7;
  unsigned char* aw0 = ldsA + r0_ * 128 + ((kc0 ^ (r0_ & 7)) << 4);
  unsigned char* aw1 = ldsA + r1_ * 128 + ((kc1 ^ (r1_ & 7)) << 4);
  const float* gA0 = x + (size_t)(m0 + r0_) * D_DIM + kc0 * 8;
  const float* gA1 = x + (size_t)(m0 + r1_) * D_DIM + kc1 * 8;

  f32x4_t acc[2][4];
#pragma unroll
  for (int mf = 0; mf < 2; ++mf)
#pragma unroll
    for (int nf = 0; nf < 4; ++nf) acc[mf][nf] = (f32x4_t){0.f, 0.f, 0.f, 0.f};

  union { __hip_bfloat16 h[8]; uint4 u; } pk;
  float4 ar[4];  // in-flight A f32 regs (2 chunks x 2 float4)

  auto cvt_write = [&]() {
    pk.h[0] = __float2bfloat16(ar[0].x); pk.h[1] = __float2bfloat16(ar[0].y);
    pk.h[2] = __float2bfloat16(ar[0].z); pk.h[3] = __float2bfloat16(ar[0].w);
    pk.h[4] = __float2bfloat16(ar[1].x); pk.h[5] = __float2bfloat16(ar[1].y);
    pk.h[6] = __float2bfloat16(ar[1].z); pk.h[7] = __float2bfloat16(ar[1].w);
    *reinterpret_cast<uint4*>(aw0) = pk.u;
    pk.h[0] = __float2bfloat16(ar[2].x); pk.h[1] = __float2bfloat16(ar[2].y);
    pk.h[2] = __float2bfloat16(ar[2].z); pk.h[3] = __float2bfloat16(ar[2].w);
    pk.h[4] = __float2bfloat16(ar[3].x); pk.h[5] = __float2bfloat16(ar[3].y);
    pk.h[6] = __float2bfloat16(ar[3].z); pk.h[7] = __float2bfloat16(ar[3].w);
    *reinterpret_cast<uint4*>(aw1) = pk.u;
  };

  // ---- prologue: stage step 0 (no compute to hide; plain sync) ----
  {
    const int k0 = (kg * 4) * 64;
    ar[0] = *reinterpret_cast<const float4*>(gA0 + k0);
    ar[1] = *reinterpret_cast<const float4*>(gA0 + k0 + 4);
    ar[2] = *reinterpret_cast<const float4*>(gA1 + k0);
    ar[3] = *reinterpret_cast<const float4*>(gA1 + k0 + 4);
#pragma unroll
    for (int ph = 0; ph < 4; ++ph) {
      const int c = ph * 256 + tid;
      async_ld16(wbt + (size_t)(kg * 4) * 8192 + c * 8, &ldsB[0][c * 16]);
    }
    cvt_write();
    __syncthreads();   // drains everything once
  }

  for (int kk = 0; kk < 4; ++kk) {
    const int cur = kk & 1;
    // ---- fragments from ldsA (single) + ldsB[cur] ----
    union fragu { uint4 u; bf16x8_t v; };
    fragu af[2][2], bf_[4][2];
#pragma unroll
    for (int mf = 0; mf < 2; ++mf)
#pragma unroll
      for (int ks = 0; ks < 2; ++ks) {
        const int arr = wm * 32 + mf * 16 + fr;
        const int kq = ks * 4 + fq;
        af[mf][ks].u = *reinterpret_cast<const uint4*>(
            ldsA + arr * 128 + ((kq ^ (arr & 7)) * 16));
      }
#pragma unroll
    for (int nf = 0; nf < 4; ++nf)
#pragma unroll
      for (int ks = 0; ks < 2; ++ks) {
        const int br = wn * 64 + nf * 16 + fr;
        const int kq = ks * 4 + fq;
        bf_[nf][ks].u = *reinterpret_cast<const uint4*>(
            ldsB[cur] + br * 128 + ((kq ^ (br & 7)) * 16));
      }
    // ---- issue next-step loads: A first (so cvt waits vmcnt(16)), then B ----
    if (kk < 3) {
      const int k0n = (kg * 4 + kk + 1) * 64;
      ar[0] = *reinterpret_cast<const float4*>(gA0 + k0n);
      ar[1] = *reinterpret_cast<const float4*>(gA0 + k0n + 4);
      ar[2] = *reinterpret_cast<const float4*>(gA1 + k0n);
      ar[3] = *reinterpret_cast<const float4*>(gA1 + k0n + 4);
      __builtin_amdgcn_sched_barrier(0);
#pragma unroll
      for (int ph = 0; ph < 4; ++ph) {
        const int c = ph * 256 + tid;
        async_ld16(wbt + (size_t)(kg * 4 + kk + 1) * 8192 + c * 8,
                   &ldsB[cur ^ 1][c * 16]);
      }
      __builtin_amdgcn_sched_barrier(0);
    }
    // ---- MFMAs on current step ----
#pragma unroll
    for (int mf = 0; mf < 2; ++mf)
#pragma unroll
      for (int nf = 0; nf < 4; ++nf) {
        acc[mf][nf] = __builtin_amdgcn_mfma_f32_16x16x32_bf16(
            af[mf][0].v, bf_[nf][0].v, acc[mf][nf], 0, 0, 0);
        acc[mf][nf] = __builtin_amdgcn_mfma_f32_16x16x32_bf16(
            af[mf][1].v, bf_[nf][1].v, acc[mf][nf], 0, 0, 0);
      }
    // ---- barrier 1: all waves done READING ldsA/ldsB[cur]; B stays in flight --
    asm volatile("s_waitcnt lgkmcnt(0)" ::: "memory");
    __builtin_amdgcn_s_barrier();
    __builtin_amdgcn_sched_barrier(0);
    if (kk < 3) {
      cvt_write();   // compiler emits counted vmcnt for ar (B-gloads still out)
    }
    // ---- barrier 2: own B-gloads + A ds_writes complete, then all waves ----
    asm volatile("s_waitcnt vmcnt(0) lgkmcnt(0)" ::: "memory");
    __builtin_amdgcn_s_barrier();
    __builtin_amdgcn_sched_barrier(0);
  }

  // ---- epilogue: direct f32 stores of partials (R4/R7-verified layout) ----
#pragma unroll
  for (int mf = 0; mf < 2; ++mf)
#pragma unroll
    for (int nf = 0; nf < 4; ++nf)
#pragma unroll
      for (int reg = 0; reg < 4; ++reg) {
        const int r = m0 + wm * 32 + mf * 16 + fq * 4 + reg;
        const int c = wn * 64 + nf * 16 + fr;
        part[((size_t)kg * 8192 + r) * 128 + c] = acc[mf][nf][reg];
      }
}

// ---------------- kernel 4: reduce partials + normalize + gelu + combine ----
__global__ __launch_bounds__(256) void k_finish(const float* __restrict__ part,
                                                const float* __restrict__ gw,
                                                float* __restrict__ out) {
  __shared__ float z[32 * 132];
  __shared__ float ps[32 * 8];
  const int tid = threadIdx.x;
  const int m0 = blockIdx.x * 32;   // 256 blocks
  const float g0 = gw[0], g1 = gw[1];
  const size_t KSTRIDE = (size_t)8192 * 128;
#pragma unroll
  for (int p = 0; p < 4; ++p) {
    const int idx = p * 256 + tid;
    const int r = idx >> 5, c4 = (idx & 31) * 4;
    const float* pp = part + ((size_t)(m0 + r)) * 128 + c4;
    f32x4_t s = (f32x4_t){0.f, 0.f, 0.f, 0.f};
#pragma unroll
    for (int kgi = 0; kgi < 8; ++kgi)
      s = s + *reinterpret_cast<const f32x4_t*>(pp + kgi * KSTRIDE);
    z[r * 132 + c4 + 0] = s[0];
    z[r * 132 + c4 + 1] = s[1];
    z[r * 132 + c4 + 2] = s[2];
    z[r * 132 + c4 + 3] = s[3];
  }
  __syncthreads();
  {
    const int r = tid >> 3, seg = tid & 7;
    float s = 0.f;
#pragma unroll
    for (int i2 = 0; i2 < 16; ++i2) {
      const float t2 = z[r * 132 + seg * 16 + i2];
      s += t2 * t2;
    }
    ps[r * 8 + seg] = s;
  }
  __syncthreads();
  {
    const int r = tid >> 3, j = tid & 7;
    const float s0 = ps[r * 8 + 0] + ps[r * 8 + 1] + ps[r * 8 + 2] + ps[r * 8 + 3];
    const float s1 = ps[r * 8 + 4] + ps[r * 8 + 5] + ps[r * 8 + 6] + ps[r * 8 + 7];
    const float i0 = 1.0f / fmaxf(sqrtf(s0), 1e-12f);
    const float i1 = 1.0f / fmaxf(sqrtf(s1), 1e-12f);
    float o[8];
#pragma unroll
    for (int i2 = 0; i2 < 8; ++i2) {
      const int c = j * 8 + i2;
      const float za = z[r * 132 + c] * i0;
      const float zb2 = z[r * 132 + 64 + c] * i1;
      o[i2] = g0 * gelu_f(za) + g1 * gelu_f(zb2);
    }
    float4* op = reinterpret_cast<float4*>(out + (size_t)(m0 + r) * 64 + j * 8);
    op[0] = make_float4(o[0], o[1], o[2], o[3]);
    op[1] = make_float4(o[4], o[5], o[6], o[7]);
  }
}

// ---------------- launch ----------------
extern "C" void kernel_launch(void* const* d_in, const int* in_sizes, int n_in,
                              void* d_out, int out_size, void* d_ws, size_t ws_size,
                              hipStream_t stream) {
  (void)in_sizes; (void)n_in; (void)out_size; (void)ws_size;
  const float* x      = (const float*)d_in[0];
  const float* wg_in  = (const float*)d_in[1];
  const float* wg_lin = (const float*)d_in[2];
  const float* wg_out = (const float*)d_in[3];
  const float* we     = (const float*)d_in[4];
  float* out = (float*)d_out;
  char* ws = (char*)d_ws;

  float* upart = (float*)(ws + WS_UPART);
  float* u     = (float*)(ws + WS_U);
  float* v     = (float*)(ws + WS_V);
  int*   sel   = (int*)(ws + WS_META);
  float* g     = (float*)(ws + WS_META + 8);
  __hip_bfloat16* wbt = (__hip_bfloat16*)(ws + WS_WB);
  float* part = (float*)(ws + WS_PART);

  k_upart  <<<dim3(2, 128), 256, 0, stream>>>(x, wg_out, upart);
  k_ufinish<<<8, 256, 0, stream>>>(upart, u);
  k_v      <<<64, 256, 0, stream>>>(wg_in, u, v);
  k_gate   <<<1, 64, 0, stream>>>(wg_lin, v, sel, g);
  k_wb     <<<128, 256, 0, stream>>>(we, sel, wbt);
  k_moe_gemm<<<dim3(128, 8), 256, 0, stream>>>(x, wbt, part);
  k_finish <<<256, 256, 0, stream>>>(part, g, out);
}